// Round 1
// baseline (256.559 us; speedup 1.0000x reference)
//
#include <hip/hip_runtime.h>
#include <hip/hip_fp16.h>

// ResidualDenoiser: 4 chained GEMMs + BN/ReLU + ragged segment softmax.
// Activations live in one persistent fp16 buffer H[8192][3328] laid out
// [A3 | A2 | A1 | A0=x] so each layer's concatenated input is H + colOff.
//   layer0: in H+3072 (K= 256) -> out cols 2048:3072
//   layer1: in H+2048 (K=1280) -> out cols 1024:2048
//   layer2: in H+1024 (K=2304) -> out cols    0:1024
//   layer3: in H+0    (K=3328) -> splitK=4 atomicAdd fp32 into out (bias
//           pre-applied by prep), then separate segment-softmax dispatch.
// LESSONS (measured R4/R5/R6): in-kernel cross-block sync costs 300-450 us
// on this 8-XCD part — dispatch boundaries ARE the cheap sync.
//
// R7 (this round): GEMM structure upgrade. The previous 128x128 / 4-wave /
// __syncthreads kernel sat at ~870 TF = the known 2-barrier-drain ceiling
// (every K-step drains vmcnt(0) before s_barrier). New structure per the
// measured 8-phase recipe: BM=256 x BN=128, BK=64, 8 waves (4Mx2N, 64x64
// each), THREE LDS buffers (144 KB dynamic) rotating with prefetch distance
// 2 K-tiles, counted s_waitcnt vmcnt(8) (never 0 in steady state), raw
// s_barrier, per-quadrant MFMA clusters wrapped in s_setprio.
// Buffer lifetime proof: tile t+2 is issued during iter t into buf[(t+2)%3],
// which held tile t-1, released by the barrier ending iter t-1 — so the
// async LDS writes can never land on live data. vmcnt(8) at iter t phase 0
// = 6 outstanding (tile t+1) + 2 just-issued (tile t+2) => tile t landed.
// Tail: iter nt-2 waits vmcnt(6), iter nt-1 waits vmcnt(0).

#define LDH 3328
#define NROWS 8192

typedef _Float16 f16x8 __attribute__((ext_vector_type(8)));
typedef _Float16 f16x4 __attribute__((ext_vector_type(4)));
typedef float f32x4 __attribute__((ext_vector_type(4)));

__constant__ int c_bnd[11] = {0, 2, 5, 10, 18, 31, 52, 86, 141, 230, 256};

// async global->LDS, 16B per lane; LDS dest is wave-uniform base + lane*16.
__device__ __forceinline__ void async_cp16(const _Float16* g, _Float16* l) {
  __builtin_amdgcn_global_load_lds(
      (__attribute__((address_space(1))) void*)g,
      (__attribute__((address_space(3))) void*)l, 16, 0, 0);
}

__device__ __forceinline__ _Float16 f2h(float f) { return (_Float16)f; }

// ---------------------------------------------------------------------------
// prep: weights fp32->fp16 (contiguous), x staged into H, out = bias.
// One float4-group per thread.
__global__ void prep_kernel(const float* __restrict__ s0,
                            const float* __restrict__ s1,
                            const float* __restrict__ s2,
                            const float* __restrict__ s3,
                            const float* __restrict__ x,
                            const float* __restrict__ b3,
                            _Float16* __restrict__ d0,
                            _Float16* __restrict__ d1,
                            _Float16* __restrict__ d2,
                            _Float16* __restrict__ d3,
                            _Float16* __restrict__ H, float* __restrict__ out,
                            int n0, int n1, int n2, int n3, int n4, int n5) {
  int i = blockIdx.x * blockDim.x + threadIdx.x;
  if (i >= n5) return;
  if (i >= n4) {  // out[8192][256] = broadcast bias b3
    const int j = i - n4;
    const int c = (j & 63) * 4;
    *(float4*)&out[(size_t)j * 4] = *(const float4*)&b3[c];
    return;
  }
  if (i >= n3) {  // x[8192,256] -> H[:, 3072:3328]
    const int j = i - n3;
    const int row = j >> 6;
    const int c = (j & 63) * 4;
    const float4 v = *(const float4*)&x[(size_t)j * 4];
    f16x4 h = {f2h(v.x), f2h(v.y), f2h(v.z), f2h(v.w)};
    *(f16x4*)&H[(size_t)row * LDH + 3072 + c] = h;
    return;
  }
  const float* s;
  _Float16* d;
  if (i < n0) {
    s = s0; d = d0;
  } else if (i < n1) {
    s = s1 - (size_t)n0 * 4; d = d1 - (size_t)n0 * 4;
  } else if (i < n2) {
    s = s2 - (size_t)n1 * 4; d = d2 - (size_t)n1 * 4;
  } else {
    s = s3 - (size_t)n2 * 4; d = d3 - (size_t)n2 * 4;
  }
  const float4 v = *(const float4*)&s[(size_t)i * 4];
  f16x4 h = {f2h(v.x), f2h(v.y), f2h(v.z), f2h(v.w)};
  *(f16x4*)&d[(size_t)i * 4] = h;
}

// ---------------------------------------------------------------------------
// Shared 8-wave 256x128 K-loop (BK=64, 3 LDS buffers, counted vmcnt).
// LDS layout per buffer: A[256][64] then B[128][64], f16. Row = 8 chunks of
// 16B; chunk c of row r stored at slot c ^ (r&7) (XOR swizzle: conflict-free
// ds_read_b128 AND staging lands at wave-uniform-base + lane*16 exactly,
// with the swizzle applied on the GLOBAL source address).

#define BUFSZ 24576  /* f16 elems per buffer: 256*64 + 128*64 */
#define ABOFF 16384  /* B tile offset inside buffer */

// stage one 64-row group of A (quarter q) / B (half h) of the K-tile at k0.
#define STA(Ab, q, k0)                                                       \
  async_cp16(A + (size_t)(row0 + (q) * 64 + srow) * LDH + (k0) + sgc,        \
             (Ab) + ((q) * 64 + wave * 8) * 64)
#define STB(Bb, h, k0)                                                       \
  async_cp16(W + (size_t)(col0 + (h) * 64 + srow) * K + (k0) + sgc,          \
             (Bb) + ((h) * 64 + wave * 8) * 64)

#define LOADQ(QM, QN)                                                        \
  {                                                                          \
    const int ra0 = wr * 64 + (QM) * 32 + fr;                                \
    const int ra1 = ra0 + 16;                                                \
    const int rb0 = wc * 64 + (QN) * 32 + fr;                                \
    const int rb1 = rb0 + 16;                                                \
    av[0][0] = *(const f16x8*)&Ac[ra0 * 64 + ((q2 ^ (ra0 & 7)) * 8)];        \
    av[0][1] = *(const f16x8*)&Ac[ra0 * 64 + (((q2 + 4) ^ (ra0 & 7)) * 8)];  \
    av[1][0] = *(const f16x8*)&Ac[ra1 * 64 + ((q2 ^ (ra1 & 7)) * 8)];        \
    av[1][1] = *(const f16x8*)&Ac[ra1 * 64 + (((q2 + 4) ^ (ra1 & 7)) * 8)];  \
    bv[0][0] = *(const f16x8*)&Bc[rb0 * 64 + ((q2 ^ (rb0 & 7)) * 8)];        \
    bv[0][1] = *(const f16x8*)&Bc[rb0 * 64 + (((q2 + 4) ^ (rb0 & 7)) * 8)];  \
    bv[1][0] = *(const f16x8*)&Bc[rb1 * 64 + ((q2 ^ (rb1 & 7)) * 8)];        \
    bv[1][1] = *(const f16x8*)&Bc[rb1 * 64 + (((q2 + 4) ^ (rb1 & 7)) * 8)];  \
  }

#define MF(a, b, c) __builtin_amdgcn_mfma_f32_16x16x32_f16(a, b, c, 0, 0, 0)

#define MFMAQ(QM, QN)                                                         \
  __builtin_amdgcn_s_setprio(1);                                              \
  acc[(QM)*2+0][(QN)*2+0] = MF(av[0][0], bv[0][0], acc[(QM)*2+0][(QN)*2+0]);  \
  acc[(QM)*2+0][(QN)*2+1] = MF(av[0][0], bv[1][0], acc[(QM)*2+0][(QN)*2+1]);  \
  acc[(QM)*2+1][(QN)*2+0] = MF(av[1][0], bv[0][0], acc[(QM)*2+1][(QN)*2+0]);  \
  acc[(QM)*2+1][(QN)*2+1] = MF(av[1][0], bv[1][0], acc[(QM)*2+1][(QN)*2+1]);  \
  acc[(QM)*2+0][(QN)*2+0] = MF(av[0][1], bv[0][1], acc[(QM)*2+0][(QN)*2+0]);  \
  acc[(QM)*2+0][(QN)*2+1] = MF(av[0][1], bv[1][1], acc[(QM)*2+0][(QN)*2+1]);  \
  acc[(QM)*2+1][(QN)*2+0] = MF(av[1][1], bv[0][1], acc[(QM)*2+1][(QN)*2+0]);  \
  acc[(QM)*2+1][(QN)*2+1] = MF(av[1][1], bv[1][1], acc[(QM)*2+1][(QN)*2+1]);  \
  __builtin_amdgcn_s_setprio(0);

// One K-tile iteration: 4 phases (quadrants), tile t+2's 6 loads spread
// across phases, counted vmcnt at phase 0, raw barriers only.
#define GITER(VMSTR, ISS, k0n)                                               \
  {                                                                          \
    _Float16* Ac = lds_ + cur * BUFSZ;                                       \
    _Float16* Bc = Ac + ABOFF;                                               \
    _Float16* An = lds_ + nxt * BUFSZ;                                       \
    _Float16* Bn = An + ABOFF;                                               \
    f16x8 av[2][2], bv[2][2];                                                \
    if (ISS) { STA(An, 0, k0n); STA(An, 1, k0n); }                           \
    asm volatile("s_waitcnt " VMSTR ::: "memory");                           \
    __builtin_amdgcn_s_barrier();                                            \
    LOADQ(0, 0);                                                             \
    MFMAQ(0, 0);                                                             \
    __builtin_amdgcn_s_barrier();                                            \
    if (ISS) { STA(An, 2, k0n); STA(An, 3, k0n); }                           \
    LOADQ(0, 1);                                                             \
    __builtin_amdgcn_s_barrier();                                            \
    MFMAQ(0, 1);                                                             \
    __builtin_amdgcn_s_barrier();                                            \
    if (ISS) { STB(Bn, 0, k0n); }                                            \
    LOADQ(1, 0);                                                             \
    __builtin_amdgcn_s_barrier();                                            \
    MFMAQ(1, 0);                                                             \
    __builtin_amdgcn_s_barrier();                                            \
    if (ISS) { STB(Bn, 1, k0n); }                                            \
    LOADQ(1, 1);                                                             \
    __builtin_amdgcn_s_barrier();                                            \
    MFMAQ(1, 1);                                                             \
    __builtin_amdgcn_s_barrier();                                            \
  }

__device__ __forceinline__ void gemm_loop(const _Float16* __restrict__ A,
                                          const _Float16* __restrict__ W,
                                          int K, int kbase, int nt, int row0,
                                          int col0, int tid, _Float16* lds_,
                                          f32x4 (&acc)[4][4]) {
  const int lane = tid & 63;
  const int wave = tid >> 6;   // 0..7
  const int wr = wave >> 1;    // 0..3 : 64-row slice
  const int wc = wave & 1;     // 0..1 : 64-col slice
  const int fr = lane & 15;
  const int q2 = lane >> 4;
  const int srow = tid >> 3;                       // staging row 0..63
  const int sgc = ((tid & 7) ^ (srow & 7)) * 8;    // pre-swizzled chunk

  // prologue: stage tiles 0 and 1 (12 loads), no wait (deferred to iter 0).
  {
    _Float16* A0 = lds_;
    _Float16* B0 = lds_ + ABOFF;
    STA(A0, 0, kbase); STA(A0, 1, kbase); STA(A0, 2, kbase); STA(A0, 3, kbase);
    STB(B0, 0, kbase); STB(B0, 1, kbase);
    _Float16* A1 = lds_ + BUFSZ;
    _Float16* B1 = A1 + ABOFF;
    STA(A1, 0, kbase + 64); STA(A1, 1, kbase + 64);
    STA(A1, 2, kbase + 64); STA(A1, 3, kbase + 64);
    STB(B1, 0, kbase + 64); STB(B1, 1, kbase + 64);
  }

  int cur = 0, nxt = 2;
  int t = 0;
  for (; t + 2 < nt; ++t) {
    const int k0n = kbase + (t + 2) * 64;
    GITER("vmcnt(8)", 1, k0n);
    cur = cur == 2 ? 0 : cur + 1;
    nxt = nxt == 2 ? 0 : nxt + 1;
  }
  {
    const int k0n = 0;
    GITER("vmcnt(6)", 0, k0n);  // t = nt-2: only tile nt-1's 6 outstanding
    cur = cur == 2 ? 0 : cur + 1;
    GITER("vmcnt(0)", 0, k0n);  // t = nt-1: drain
  }
}

// ---------------------------------------------------------------------------
// Layers 0-2: C = relu(bn(A[256,K] @ W[128,K]^T)) -> fp16 into H.
// Grid dim3(32,8), 512 threads, 144 KB dynamic LDS (1 block/CU, 8 waves).
__launch_bounds__(512, 2) __global__
void gemm_bn_8ph(const _Float16* __restrict__ A, int K,
                 const _Float16* __restrict__ W,
                 const float* __restrict__ bias,
                 const float* __restrict__ g, const float* __restrict__ be,
                 const float* __restrict__ rm, const float* __restrict__ rv,
                 _Float16* __restrict__ outH, int outOff) {
  extern __shared__ _Float16 lds_[];
  const int tid = threadIdx.x;
  const int lane = tid & 63;
  const int wave = tid >> 6;
  const int wr = wave >> 1;
  const int wc = wave & 1;
  const int fr = lane & 15;
  const int q2 = lane >> 4;
  const int row0 = blockIdx.x * 256;
  const int col0 = blockIdx.y * 128;

  f32x4 acc[4][4] = {};
  gemm_loop(A, W, K, 0, K >> 6, row0, col0, tid, lds_, acc);

  // Epilogue. C/D layout: col = lane&15, row = (lane>>4)*4 + reg.
#pragma unroll
  for (int tn = 0; tn < 4; ++tn) {
    const int n = col0 + wc * 64 + tn * 16 + fr;
    const float alpha = g[n] * rsqrtf(rv[n] + 1e-5f);
    const float beta = (bias[n] - rm[n]) * alpha + be[n];
#pragma unroll
    for (int tm = 0; tm < 4; ++tm) {
      const int rbase = row0 + wr * 64 + tm * 16 + q2 * 4;
#pragma unroll
      for (int r = 0; r < 4; ++r) {
        float v = acc[tm][tn][r] * alpha + beta;
        v = fmaxf(v, 0.0f);
        outH[(size_t)(rbase + r) * LDH + outOff + n] = f2h(v);
      }
    }
  }
}

// ---------------------------------------------------------------------------
// Layer 3: same loop, splitK=4 (832 = 13*64 per slice). Grid dim3(32,8):
// cb=by&1 (col tile), ks=by>>1. Partials atomicAdd into out (bias
// pre-applied by prep).
__launch_bounds__(512, 2) __global__
void gemm_out_8ph(const _Float16* __restrict__ A,
                  const _Float16* __restrict__ W, float* __restrict__ out) {
  extern __shared__ _Float16 lds_[];
  const int tid = threadIdx.x;
  const int lane = tid & 63;
  const int wave = tid >> 6;
  const int wr = wave >> 1;
  const int wc = wave & 1;
  const int fr = lane & 15;
  const int q2 = lane >> 4;
  const int row0 = blockIdx.x * 256;
  const int cb = blockIdx.y & 1;
  const int ks = blockIdx.y >> 1;
  const int col0 = cb * 128;
  const int K = 3328;

  f32x4 acc[4][4] = {};
  gemm_loop(A, W, K, ks * 832, 13, row0, col0, tid, lds_, acc);

#pragma unroll
  for (int tn = 0; tn < 4; ++tn) {
    const int n = col0 + wc * 64 + tn * 16 + fr;
#pragma unroll
    for (int tm = 0; tm < 4; ++tm) {
      const int rbase = row0 + wr * 64 + tm * 16 + q2 * 4;
#pragma unroll
      for (int r = 0; r < 4; ++r)
        atomicAdd(&out[(size_t)(rbase + r) * 256 + n], acc[tm][tn][r]);
    }
  }
}

// ---------------------------------------------------------------------------
// ragged segment softmax, in place on out[8192][256]; 4 rows/block (1/wave).
__global__ void segsoftmax_kernel(float* __restrict__ out,
                                  const int* __restrict__ segids) {
  __shared__ float vals[4][256];
  __shared__ float red[4][10];
  const int w = threadIdx.x >> 6;
  const int l = threadIdx.x & 63;
  const int row = blockIdx.x * 4 + w;
  float4 v = *(float4*)&out[(size_t)row * 256 + l * 4];
  *(float4*)&vals[w][l * 4] = v;
  __syncthreads();
  if (l < 10) {
    float m = -1e30f;
    for (int j = c_bnd[l]; j < c_bnd[l + 1]; ++j) m = fmaxf(m, vals[w][j]);
    red[w][l] = m;
  }
  __syncthreads();
  const int4 s4 = *(const int4*)&segids[l * 4];
  float4 e;
  e.x = expf(v.x - red[w][s4.x]);
  e.y = expf(v.y - red[w][s4.y]);
  e.z = expf(v.z - red[w][s4.z]);
  e.w = expf(v.w - red[w][s4.w]);
  *(float4*)&vals[w][l * 4] = e;
  __syncthreads();
  if (l < 10) {
    float s = 0.0f;
    for (int j = c_bnd[l]; j < c_bnd[l + 1]; ++j) s += vals[w][j];
    red[w][l] = s;
  }
  __syncthreads();
  float4 o;
  o.x = e.x / red[w][s4.x];
  o.y = e.y / red[w][s4.y];
  o.z = e.z / red[w][s4.z];
  o.w = e.w / red[w][s4.w];
  *(float4*)&out[(size_t)row * 256 + l * 4] = o;
}

// ---------------------------------------------------------------------------
extern "C" void kernel_launch(void* const* d_in, const int* in_sizes, int n_in,
                              void* d_out, int out_size, void* d_ws,
                              size_t ws_size, hipStream_t stream) {
  const float* x = (const float*)d_in[0];
  const float* W0 = (const float*)d_in[1];
  const float* b0 = (const float*)d_in[2];
  const float* g0 = (const float*)d_in[3];
  const float* be0 = (const float*)d_in[4];
  const float* rm0 = (const float*)d_in[5];
  const float* rv0 = (const float*)d_in[6];
  const float* W1 = (const float*)d_in[7];
  const float* b1 = (const float*)d_in[8];
  const float* g1 = (const float*)d_in[9];
  const float* be1 = (const float*)d_in[10];
  const float* rm1 = (const float*)d_in[11];
  const float* rv1 = (const float*)d_in[12];
  const float* W2 = (const float*)d_in[13];
  const float* b2 = (const float*)d_in[14];
  const float* g2 = (const float*)d_in[15];
  const float* be2 = (const float*)d_in[16];
  const float* rm2 = (const float*)d_in[17];
  const float* rv2 = (const float*)d_in[18];
  const float* W3 = (const float*)d_in[19];
  const float* b3 = (const float*)d_in[20];
  const int* seg = (const int*)d_in[21];
  float* out = (float*)d_out;

  // ws (fp16): H[8192*3328] | Wh0 | Wh1 | Wh2 | Wh3  (~64.1 MB)
  _Float16* H = (_Float16*)d_ws;
  size_t off = (size_t)NROWS * LDH;
  _Float16* Wh0 = H + off; off += 1024 * 256;
  _Float16* Wh1 = H + off; off += 1024 * 1280;
  _Float16* Wh2 = H + off; off += 1024 * 2304;
  _Float16* Wh3 = H + off;

  static bool attr_done = false;
  if (!attr_done) {
    hipFuncSetAttribute(reinterpret_cast<const void*>(gemm_bn_8ph),
                        hipFuncAttributeMaxDynamicSharedMemorySize, 147456);
    hipFuncSetAttribute(reinterpret_cast<const void*>(gemm_out_8ph),
                        hipFuncAttributeMaxDynamicSharedMemorySize, 147456);
    attr_done = true;
  }

  // cumulative float4 counts: W0, W1, W2, W3, x, out-init
  const int n0 = 65536, n1 = n0 + 327680, n2 = n1 + 589824, n3 = n2 + 212992;
  const int n4 = n3 + 524288, n5 = n4 + 524288;
  prep_kernel<<<(n5 + 255) / 256, 256, 0, stream>>>(
      W0, W1, W2, W3, x, b3, Wh0, Wh1, Wh2, Wh3, H, out, n0, n1, n2, n3, n4,
      n5);

  gemm_bn_8ph<<<dim3(32, 8), 512, 147456, stream>>>(
      H + 3072, 256, Wh0, b0, g0, be0, rm0, rv0, H, 2048);
  gemm_bn_8ph<<<dim3(32, 8), 512, 147456, stream>>>(
      H + 2048, 1280, Wh1, b1, g1, be1, rm1, rv1, H, 1024);
  gemm_bn_8ph<<<dim3(32, 8), 512, 147456, stream>>>(
      H + 1024, 2304, Wh2, b2, g2, be2, rm2, rv2, H, 0);
  gemm_out_8ph<<<dim3(32, 8), 512, 147456, stream>>>(H, Wh3, out);
  segsoftmax_kernel<<<2048, 256, 0, stream>>>(out, seg);
}

// Round 2
// 245.950 us; speedup vs baseline: 1.0431x; 1.0431x over previous
//
#include <hip/hip_runtime.h>
#include <hip/hip_fp16.h>

// ResidualDenoiser: 4 chained GEMMs + BN/ReLU + ragged segment softmax.
// Activations live in one persistent fp16 buffer H[8192][3328] laid out
// [A3 | A2 | A1 | A0=x] so each layer's concatenated input is H + colOff.
//   layer0: in H+3072 (K= 256) -> out cols 2048:3072
//   layer1: in H+2048 (K=1280) -> out cols 1024:2048
//   layer2: in H+1024 (K=2304) -> out cols    0:1024
//   layer3: in H+0    (K=3328) -> splitK=4 atomicAdd fp32 into out (bias
//           pre-applied by prep), then separate segment-softmax dispatch.
// LESSONS:
//  R4-R6: in-kernel cross-block sync costs 300-450 us — keep dispatches.
//  R7 (FAILED, 57us/layer2): __launch_bounds__(512,2) capped unified regs at
//    128 (VGPR 64 + AGPR 64) -> ~90B/thread scratch spill (WRITE_SIZE
//    16.5->27.8MB), MfmaUtil 25%. Also 4 MFMA/barrier (template needs 8).
//  R8 (this round): launch_bounds(512,1) (no spill); 2 phases per K-tile,
//    16 MFMA per phase (8 MFMA/barrier); ds_reads issued BEFORE the phase
//    barrier so they overlap the previous phase's MFMA drain; per-K-tile
//    counted vmcnt(6) (never 0 in steady state); 3 LDS buffers (144KB),
//    prefetch distance 2.
// Buffer lifetime: tile t+2 is issued during iter t into buf[(t+2)%3] ==
// buf[(t-1)%3], whose readers all finished before iter t-1's closing
// barrier (lgkmcnt(0) precedes it). vmcnt(6) at iter t phase 1: outstanding
// = t+2's 6 loads (all issued) + t+1's remainder; waiting to 6 proves tile
// t+1 landed before any wave reads it in iter t+1.

#define LDH 3328
#define NROWS 8192

typedef _Float16 f16x8 __attribute__((ext_vector_type(8)));
typedef _Float16 f16x4 __attribute__((ext_vector_type(4)));
typedef float f32x4 __attribute__((ext_vector_type(4)));

__constant__ int c_bnd[11] = {0, 2, 5, 10, 18, 31, 52, 86, 141, 230, 256};

// async global->LDS, 16B per lane; LDS dest is wave-uniform base + lane*16.
__device__ __forceinline__ void async_cp16(const _Float16* g, _Float16* l) {
  __builtin_amdgcn_global_load_lds(
      (__attribute__((address_space(1))) void*)g,
      (__attribute__((address_space(3))) void*)l, 16, 0, 0);
}

__device__ __forceinline__ _Float16 f2h(float f) { return (_Float16)f; }

// ---------------------------------------------------------------------------
// prep: weights fp32->fp16 (contiguous), x staged into H, out = bias.
// One float4-group per thread.
__global__ void prep_kernel(const float* __restrict__ s0,
                            const float* __restrict__ s1,
                            const float* __restrict__ s2,
                            const float* __restrict__ s3,
                            const float* __restrict__ x,
                            const float* __restrict__ b3,
                            _Float16* __restrict__ d0,
                            _Float16* __restrict__ d1,
                            _Float16* __restrict__ d2,
                            _Float16* __restrict__ d3,
                            _Float16* __restrict__ H, float* __restrict__ out,
                            int n0, int n1, int n2, int n3, int n4, int n5) {
  int i = blockIdx.x * blockDim.x + threadIdx.x;
  if (i >= n5) return;
  if (i >= n4) {  // out[8192][256] = broadcast bias b3
    const int j = i - n4;
    const int c = (j & 63) * 4;
    *(float4*)&out[(size_t)j * 4] = *(const float4*)&b3[c];
    return;
  }
  if (i >= n3) {  // x[8192,256] -> H[:, 3072:3328]
    const int j = i - n3;
    const int row = j >> 6;
    const int c = (j & 63) * 4;
    const float4 v = *(const float4*)&x[(size_t)j * 4];
    f16x4 h = {f2h(v.x), f2h(v.y), f2h(v.z), f2h(v.w)};
    *(f16x4*)&H[(size_t)row * LDH + 3072 + c] = h;
    return;
  }
  const float* s;
  _Float16* d;
  if (i < n0) {
    s = s0; d = d0;
  } else if (i < n1) {
    s = s1 - (size_t)n0 * 4; d = d1 - (size_t)n0 * 4;
  } else if (i < n2) {
    s = s2 - (size_t)n1 * 4; d = d2 - (size_t)n1 * 4;
  } else {
    s = s3 - (size_t)n2 * 4; d = d3 - (size_t)n2 * 4;
  }
  const float4 v = *(const float4*)&s[(size_t)i * 4];
  f16x4 h = {f2h(v.x), f2h(v.y), f2h(v.z), f2h(v.w)};
  *(f16x4*)&d[(size_t)i * 4] = h;
}

// ---------------------------------------------------------------------------
// Shared 8-wave 256x128 K-loop (BK=64, 3 LDS buffers, counted vmcnt).
// LDS layout per buffer: A[256][64] then B[128][64], f16. Row = 8 chunks of
// 16B; chunk c of row r stored at slot c ^ (r&7) (XOR swizzle: conflict-free
// ds_read_b128 AND staging lands at wave-uniform-base + lane*16 exactly,
// with the swizzle applied on the GLOBAL source address).

#define BUFSZ 24576  /* f16 elems per buffer: 256*64 + 128*64 */
#define ABOFF 16384  /* B tile offset inside buffer */

// stage one 64-row group of A (quarter q) / B (half h) of the K-tile at k0.
#define STA(Ab, q, k0)                                                       \
  async_cp16(A + (size_t)(row0 + (q) * 64 + srow) * LDH + (k0) + sgc,        \
             (Ab) + ((q) * 64 + wave * 8) * 64)
#define STB(Bb, h, k0)                                                       \
  async_cp16(W + (size_t)(col0 + (h) * 64 + srow) * K + (k0) + sgc,          \
             (Bb) + ((h) * 64 + wave * 8) * 64)

// Load all 8 fragments for 32-wide k-slice KQ (chunk q2 + 4*KQ of each row).
#define LOADK(KQ)                                                             \
  {                                                                           \
    _Pragma("unroll") for (int t = 0; t < 4; ++t) {                           \
      const int ra = wr * 64 + t * 16 + fr;                                   \
      av[t] =                                                                 \
          *(const f16x8*)&Ac[ra * 64 + (((q2 + 4 * (KQ)) ^ (ra & 7)) * 8)];   \
      const int rb = wc * 64 + t * 16 + fr;                                   \
      bv[t] =                                                                 \
          *(const f16x8*)&Bc[rb * 64 + (((q2 + 4 * (KQ)) ^ (rb & 7)) * 8)];   \
    }                                                                         \
  }

#define MF(a, b, c) __builtin_amdgcn_mfma_f32_16x16x32_f16(a, b, c, 0, 0, 0)

#define MFMAK()                                                               \
  __builtin_amdgcn_s_setprio(1);                                              \
  _Pragma("unroll") for (int tm = 0; tm < 4; ++tm)                            \
      _Pragma("unroll") for (int tn = 0; tn < 4; ++tn) acc[tm][tn] =          \
          MF(av[tm], bv[tn], acc[tm][tn]);                                    \
  __builtin_amdgcn_s_setprio(0);

// One K-tile iteration: 2 phases (k-slices), 16 MFMA each, 4 barriers.
// Tile t+2's 6 staging loads split 3+3 across the phases. vmcnt once per
// K-tile, in phase 1 (validates tile t+1 for the NEXT iteration).
#define GITER2(STG, VM, k0n)                                                  \
  {                                                                           \
    _Float16* Ac = lds_ + cur * BUFSZ;                                        \
    _Float16* Bc = Ac + ABOFF;                                                \
    _Float16* An = lds_ + nxt * BUFSZ;                                        \
    _Float16* Bn = An + ABOFF;                                                \
    f16x8 av[4], bv[4];                                                       \
    /* phase 0 (buf cur validated at end of previous iteration) */            \
    LOADK(0);                                                                 \
    if (STG) { STA(An, 0, k0n); STA(An, 1, k0n); STB(Bn, 0, k0n); }           \
    __builtin_amdgcn_s_barrier();                                             \
    asm volatile("s_waitcnt lgkmcnt(0)" ::: "memory");                        \
    MFMAK();                                                                  \
    __builtin_amdgcn_s_barrier();                                             \
    /* phase 1 */                                                             \
    LOADK(1);                                                                 \
    if (STG) { STA(An, 2, k0n); STA(An, 3, k0n); STB(Bn, 1, k0n); }           \
    asm volatile("s_waitcnt " VM ::: "memory");                               \
    __builtin_amdgcn_s_barrier();                                             \
    asm volatile("s_waitcnt lgkmcnt(0)" ::: "memory");                        \
    MFMAK();                                                                  \
    __builtin_amdgcn_s_barrier();                                             \
  }

__device__ __forceinline__ void gemm_loop(const _Float16* __restrict__ A,
                                          const _Float16* __restrict__ W,
                                          int K, int kbase, int nt, int row0,
                                          int col0, int tid, _Float16* lds_,
                                          f32x4 (&acc)[4][4]) {
  const int lane = tid & 63;
  const int wave = tid >> 6;   // 0..7
  const int wr = wave >> 1;    // 0..3 : 64-row slice
  const int wc = wave & 1;     // 0..1 : 64-col slice
  const int fr = lane & 15;
  const int q2 = lane >> 4;
  const int srow = tid >> 3;                       // staging row 0..63
  const int sgc = ((tid & 7) ^ (srow & 7)) * 8;    // pre-swizzled chunk

  // prologue: stage tiles 0 and 1 (12 loads), validate tile 0.
  {
    _Float16* A0 = lds_;
    _Float16* B0 = lds_ + ABOFF;
    STA(A0, 0, kbase); STA(A0, 1, kbase); STA(A0, 2, kbase); STA(A0, 3, kbase);
    STB(B0, 0, kbase); STB(B0, 1, kbase);
    _Float16* A1 = lds_ + BUFSZ;
    _Float16* B1 = A1 + ABOFF;
    STA(A1, 0, kbase + 64); STA(A1, 1, kbase + 64);
    STA(A1, 2, kbase + 64); STA(A1, 3, kbase + 64);
    STB(B1, 0, kbase + 64); STB(B1, 1, kbase + 64);
    asm volatile("s_waitcnt vmcnt(6)" ::: "memory");  // tile 0 landed
    __builtin_amdgcn_s_barrier();
  }

  int cur = 0, nxt = 2;
  for (int t = 0; t + 2 < nt; ++t) {
    GITER2(1, "vmcnt(6)", kbase + (t + 2) * 64);
    cur = cur == 2 ? 0 : cur + 1;
    nxt = nxt == 2 ? 0 : nxt + 1;
  }
  GITER2(0, "vmcnt(0)", 0);  // t = nt-2: drain, validates tile nt-1
  cur = cur == 2 ? 0 : cur + 1;
  GITER2(0, "vmcnt(0)", 0);  // t = nt-1: vmcnt(0) is free (0 outstanding)
}

// ---------------------------------------------------------------------------
// Layers 0-2: C = relu(bn(A[256,K] @ W[128,K]^T)) -> fp16 into H.
// Grid dim3(32,8), 512 threads, 144 KB dynamic LDS (1 block/CU, 8 waves).
// launch_bounds minWavesPerEU=1: R7's =2 capped unified regs at 128 -> spill.
__launch_bounds__(512, 1) __global__
void gemm_bn_8ph(const _Float16* __restrict__ A, int K,
                 const _Float16* __restrict__ W,
                 const float* __restrict__ bias,
                 const float* __restrict__ g, const float* __restrict__ be,
                 const float* __restrict__ rm, const float* __restrict__ rv,
                 _Float16* __restrict__ outH, int outOff) {
  extern __shared__ _Float16 lds_[];
  const int tid = threadIdx.x;
  const int lane = tid & 63;
  const int wave = tid >> 6;
  const int wr = wave >> 1;
  const int wc = wave & 1;
  const int fr = lane & 15;
  const int q2 = lane >> 4;
  const int row0 = blockIdx.x * 256;
  const int col0 = blockIdx.y * 128;

  f32x4 acc[4][4] = {};
  gemm_loop(A, W, K, 0, K >> 6, row0, col0, tid, lds_, acc);

  // Epilogue. C/D layout: col = lane&15, row = (lane>>4)*4 + reg.
#pragma unroll
  for (int tn = 0; tn < 4; ++tn) {
    const int n = col0 + wc * 64 + tn * 16 + fr;
    const float alpha = g[n] * rsqrtf(rv[n] + 1e-5f);
    const float beta = (bias[n] - rm[n]) * alpha + be[n];
#pragma unroll
    for (int tm = 0; tm < 4; ++tm) {
      const int rbase = row0 + wr * 64 + tm * 16 + q2 * 4;
#pragma unroll
      for (int r = 0; r < 4; ++r) {
        float v = acc[tm][tn][r] * alpha + beta;
        v = fmaxf(v, 0.0f);
        outH[(size_t)(rbase + r) * LDH + outOff + n] = f2h(v);
      }
    }
  }
}

// ---------------------------------------------------------------------------
// Layer 3: same loop, splitK=4 (832 = 13*64 per slice). Grid dim3(32,8):
// cb=by&1 (col tile), ks=by>>1. Partials atomicAdd into out (bias
// pre-applied by prep).
__launch_bounds__(512, 1) __global__
void gemm_out_8ph(const _Float16* __restrict__ A,
                  const _Float16* __restrict__ W, float* __restrict__ out) {
  extern __shared__ _Float16 lds_[];
  const int tid = threadIdx.x;
  const int lane = tid & 63;
  const int wave = tid >> 6;
  const int wr = wave >> 1;
  const int wc = wave & 1;
  const int fr = lane & 15;
  const int q2 = lane >> 4;
  const int row0 = blockIdx.x * 256;
  const int cb = blockIdx.y & 1;
  const int ks = blockIdx.y >> 1;
  const int col0 = cb * 128;
  const int K = 3328;

  f32x4 acc[4][4] = {};
  gemm_loop(A, W, K, ks * 832, 13, row0, col0, tid, lds_, acc);

#pragma unroll
  for (int tn = 0; tn < 4; ++tn) {
    const int n = col0 + wc * 64 + tn * 16 + fr;
#pragma unroll
    for (int tm = 0; tm < 4; ++tm) {
      const int rbase = row0 + wr * 64 + tm * 16 + q2 * 4;
#pragma unroll
      for (int r = 0; r < 4; ++r)
        atomicAdd(&out[(size_t)(rbase + r) * 256 + n], acc[tm][tn][r]);
    }
  }
}

// ---------------------------------------------------------------------------
// ragged segment softmax, in place on out[8192][256]; 4 rows/block (1/wave).
__global__ void segsoftmax_kernel(float* __restrict__ out,
                                  const int* __restrict__ segids) {
  __shared__ float vals[4][256];
  __shared__ float red[4][10];
  const int w = threadIdx.x >> 6;
  const int l = threadIdx.x & 63;
  const int row = blockIdx.x * 4 + w;
  float4 v = *(float4*)&out[(size_t)row * 256 + l * 4];
  *(float4*)&vals[w][l * 4] = v;
  __syncthreads();
  if (l < 10) {
    float m = -1e30f;
    for (int j = c_bnd[l]; j < c_bnd[l + 1]; ++j) m = fmaxf(m, vals[w][j]);
    red[w][l] = m;
  }
  __syncthreads();
  const int4 s4 = *(const int4*)&segids[l * 4];
  float4 e;
  e.x = expf(v.x - red[w][s4.x]);
  e.y = expf(v.y - red[w][s4.y]);
  e.z = expf(v.z - red[w][s4.z]);
  e.w = expf(v.w - red[w][s4.w]);
  *(float4*)&vals[w][l * 4] = e;
  __syncthreads();
  if (l < 10) {
    float s = 0.0f;
    for (int j = c_bnd[l]; j < c_bnd[l + 1]; ++j) s += vals[w][j];
    red[w][l] = s;
  }
  __syncthreads();
  float4 o;
  o.x = e.x / red[w][s4.x];
  o.y = e.y / red[w][s4.y];
  o.z = e.z / red[w][s4.z];
  o.w = e.w / red[w][s4.w];
  *(float4*)&out[(size_t)row * 256 + l * 4] = o;
}

// ---------------------------------------------------------------------------
extern "C" void kernel_launch(void* const* d_in, const int* in_sizes, int n_in,
                              void* d_out, int out_size, void* d_ws,
                              size_t ws_size, hipStream_t stream) {
  const float* x = (const float*)d_in[0];
  const float* W0 = (const float*)d_in[1];
  const float* b0 = (const float*)d_in[2];
  const float* g0 = (const float*)d_in[3];
  const float* be0 = (const float*)d_in[4];
  const float* rm0 = (const float*)d_in[5];
  const float* rv0 = (const float*)d_in[6];
  const float* W1 = (const float*)d_in[7];
  const float* b1 = (const float*)d_in[8];
  const float* g1 = (const float*)d_in[9];
  const float* be1 = (const float*)d_in[10];
  const float* rm1 = (const float*)d_in[11];
  const float* rv1 = (const float*)d_in[12];
  const float* W2 = (const float*)d_in[13];
  const float* b2 = (const float*)d_in[14];
  const float* g2 = (const float*)d_in[15];
  const float* be2 = (const float*)d_in[16];
  const float* rm2 = (const float*)d_in[17];
  const float* rv2 = (const float*)d_in[18];
  const float* W3 = (const float*)d_in[19];
  const float* b3 = (const float*)d_in[20];
  const int* seg = (const int*)d_in[21];
  float* out = (float*)d_out;

  // ws (fp16): H[8192*3328] | Wh0 | Wh1 | Wh2 | Wh3  (~64.1 MB)
  _Float16* H = (_Float16*)d_ws;
  size_t off = (size_t)NROWS * LDH;
  _Float16* Wh0 = H + off; off += 1024 * 256;
  _Float16* Wh1 = H + off; off += 1024 * 1280;
  _Float16* Wh2 = H + off; off += 1024 * 2304;
  _Float16* Wh3 = H + off;

  static bool attr_done = false;
  if (!attr_done) {
    hipFuncSetAttribute(reinterpret_cast<const void*>(gemm_bn_8ph),
                        hipFuncAttributeMaxDynamicSharedMemorySize, 147456);
    hipFuncSetAttribute(reinterpret_cast<const void*>(gemm_out_8ph),
                        hipFuncAttributeMaxDynamicSharedMemorySize, 147456);
    attr_done = true;
  }

  // cumulative float4 counts: W0, W1, W2, W3, x, out-init
  const int n0 = 65536, n1 = n0 + 327680, n2 = n1 + 589824, n3 = n2 + 212992;
  const int n4 = n3 + 524288, n5 = n4 + 524288;
  prep_kernel<<<(n5 + 255) / 256, 256, 0, stream>>>(
      W0, W1, W2, W3, x, b3, Wh0, Wh1, Wh2, Wh3, H, out, n0, n1, n2, n3, n4,
      n5);

  gemm_bn_8ph<<<dim3(32, 8), 512, 147456, stream>>>(
      H + 3072, 256, Wh0, b0, g0, be0, rm0, rv0, H, 2048);
  gemm_bn_8ph<<<dim3(32, 8), 512, 147456, stream>>>(
      H + 2048, 1280, Wh1, b1, g1, be1, rm1, rv1, H, 1024);
  gemm_bn_8ph<<<dim3(32, 8), 512, 147456, stream>>>(
      H + 1024, 2304, Wh2, b2, g2, be2, rm2, rv2, H, 0);
  gemm_out_8ph<<<dim3(32, 8), 512, 147456, stream>>>(H, Wh3, out);
  segsoftmax_kernel<<<2048, 256, 0, stream>>>(out, seg);
}

// Round 3
// 245.813 us; speedup vs baseline: 1.0437x; 1.0006x over previous
//
#include <hip/hip_runtime.h>
#include <hip/hip_fp16.h>

// ResidualDenoiser: 4 chained GEMMs + BN/ReLU + ragged segment softmax.
// Activations live in one persistent fp16 buffer H[8192][3328] laid out
// [A3 | A2 | A1 | A0=x] so each layer's concatenated input is H + colOff.
//   layer0: in H+3072 (K= 256) -> out cols 2048:3072
//   layer1: in H+2048 (K=1280) -> out cols 1024:2048
//   layer2: in H+1024 (K=2304) -> out cols    0:1024
//   layer3: in H+0    (K=3328) -> splitK=4 atomicAdd fp32 into out (bias
//           pre-applied by prep), then separate segment-softmax dispatch.
// LESSONS:
//  R4-R6: in-kernel cross-block sync costs 300-450 us — keep dispatches.
//  R7 (FAILED): launch_bounds(512,2) -> 128-reg cap -> spill.
//  R8 (NEUTRAL, 44.3us/layer2 = old perf): 4 barriers/K-tile lockstep the
//    CU: ~1024cy of ds_read (128KB @128B/cy) and ~1024cy of MFMA issue per
//    K-tile ALTERNATE instead of overlapping -> 33% MfmaUtil ceiling.
//  R9 (this round): ONE barrier per K-tile. Fragment reads are plain C++
//    LDS loads (compiler emits fine-grained lgkmcnt interleave, m97-style);
//    wave skew across the single barrier overlaps LDS pipe and MFMA pipe.
//    Counted vmcnt(6) before the barrier (never 0 in steady state).
// Buffer rotation safety (3 buffers, prefetch distance 2, 1 barrier/iter):
//  staging at iter t targets buf (t+2)%3 == buf (t-1)%3. Readers of that
//  buffer retired all ds_reads before issuing their last MFMA at iter t-1,
//  hence before arriving at barrier B(t-1); staging is issued after B(t-1).
//  vmcnt(6) at iter t leaves only tile t+2's 6 loads outstanding -> tile
//  t+1 landed (per wave); B(t) makes it CU-global before iter t+1 reads it.

#define LDH 3328
#define NROWS 8192

typedef _Float16 f16x8 __attribute__((ext_vector_type(8)));
typedef _Float16 f16x4 __attribute__((ext_vector_type(4)));
typedef float f32x4 __attribute__((ext_vector_type(4)));

__constant__ int c_bnd[11] = {0, 2, 5, 10, 18, 31, 52, 86, 141, 230, 256};

// async global->LDS, 16B per lane; LDS dest is wave-uniform base + lane*16.
__device__ __forceinline__ void async_cp16(const _Float16* g, _Float16* l) {
  __builtin_amdgcn_global_load_lds(
      (__attribute__((address_space(1))) void*)g,
      (__attribute__((address_space(3))) void*)l, 16, 0, 0);
}

__device__ __forceinline__ _Float16 f2h(float f) { return (_Float16)f; }

// ---------------------------------------------------------------------------
// prep: weights fp32->fp16 (contiguous), x staged into H, out = bias.
// One float4-group per thread.
__global__ void prep_kernel(const float* __restrict__ s0,
                            const float* __restrict__ s1,
                            const float* __restrict__ s2,
                            const float* __restrict__ s3,
                            const float* __restrict__ x,
                            const float* __restrict__ b3,
                            _Float16* __restrict__ d0,
                            _Float16* __restrict__ d1,
                            _Float16* __restrict__ d2,
                            _Float16* __restrict__ d3,
                            _Float16* __restrict__ H, float* __restrict__ out,
                            int n0, int n1, int n2, int n3, int n4, int n5) {
  int i = blockIdx.x * blockDim.x + threadIdx.x;
  if (i >= n5) return;
  if (i >= n4) {  // out[8192][256] = broadcast bias b3
    const int j = i - n4;
    const int c = (j & 63) * 4;
    *(float4*)&out[(size_t)j * 4] = *(const float4*)&b3[c];
    return;
  }
  if (i >= n3) {  // x[8192,256] -> H[:, 3072:3328]
    const int j = i - n3;
    const int row = j >> 6;
    const int c = (j & 63) * 4;
    const float4 v = *(const float4*)&x[(size_t)j * 4];
    f16x4 h = {f2h(v.x), f2h(v.y), f2h(v.z), f2h(v.w)};
    *(f16x4*)&H[(size_t)row * LDH + 3072 + c] = h;
    return;
  }
  const float* s;
  _Float16* d;
  if (i < n0) {
    s = s0; d = d0;
  } else if (i < n1) {
    s = s1 - (size_t)n0 * 4; d = d1 - (size_t)n0 * 4;
  } else if (i < n2) {
    s = s2 - (size_t)n1 * 4; d = d2 - (size_t)n1 * 4;
  } else {
    s = s3 - (size_t)n2 * 4; d = d3 - (size_t)n2 * 4;
  }
  const float4 v = *(const float4*)&s[(size_t)i * 4];
  f16x4 h = {f2h(v.x), f2h(v.y), f2h(v.z), f2h(v.w)};
  *(f16x4*)&d[(size_t)i * 4] = h;
}

// ---------------------------------------------------------------------------
// Shared 8-wave 256x128 K-loop (BK=64, 3 LDS buffers, counted vmcnt).
// LDS layout per buffer: A[256][64] then B[128][64], f16. Row = 8 chunks of
// 16B; chunk c of row r stored at slot c ^ (r&7) (XOR swizzle: conflict-free
// ds_read_b128 AND staging lands at wave-uniform-base + lane*16 exactly,
// with the swizzle applied on the GLOBAL source address).

#define BUFSZ 24576  /* f16 elems per buffer: 256*64 + 128*64 */
#define ABOFF 16384  /* B tile offset inside buffer */

// stage one 64-row group of A (quarter q) / B (half h) of the K-tile at k0.
#define STA(Ab, q, k0)                                                       \
  async_cp16(A + (size_t)(row0 + (q) * 64 + srow) * LDH + (k0) + sgc,        \
             (Ab) + ((q) * 64 + wave * 8) * 64)
#define STB(Bb, h, k0)                                                       \
  async_cp16(W + (size_t)(col0 + (h) * 64 + srow) * K + (k0) + sgc,          \
             (Bb) + ((h) * 64 + wave * 8) * 64)

// Load 8 fragments for 32-wide k-slice KQ into arrays AV/BV.
#define LOADK(AV, BV, KQ)                                                     \
  {                                                                           \
    _Pragma("unroll") for (int t = 0; t < 4; ++t) {                           \
      const int ra = wr * 64 + t * 16 + fr;                                   \
      AV[t] =                                                                 \
          *(const f16x8*)&Ac[ra * 64 + (((q2 + 4 * (KQ)) ^ (ra & 7)) * 8)];   \
      const int rb = wc * 64 + t * 16 + fr;                                   \
      BV[t] =                                                                 \
          *(const f16x8*)&Bc[rb * 64 + (((q2 + 4 * (KQ)) ^ (rb & 7)) * 8)];   \
    }                                                                         \
  }

#define MF(a, b, c) __builtin_amdgcn_mfma_f32_16x16x32_f16(a, b, c, 0, 0, 0)

#define MFMAK(AV, BV)                                                         \
  _Pragma("unroll") for (int tm = 0; tm < 4; ++tm)                            \
      _Pragma("unroll") for (int tn = 0; tn < 4; ++tn) acc[tm][tn] =          \
          MF(AV[tm], BV[tn], acc[tm][tn]);

// One K-tile iteration, ONE barrier. Interior scheduling left to the
// compiler (plain LDS loads -> fine-grained lgkmcnt interleave with MFMA).
#define GITER1(STG, VM, k0n)                                                  \
  {                                                                           \
    _Float16* Ac = lds_ + cur * BUFSZ;                                        \
    _Float16* Bc = Ac + ABOFF;                                                \
    _Float16* An = lds_ + nxt * BUFSZ;                                        \
    _Float16* Bn = An + ABOFF;                                                \
    f16x8 av[4], bv[4], aw[4], bw[4];                                         \
    if (STG) { STA(An, 0, k0n); STA(An, 1, k0n); STB(Bn, 0, k0n); }           \
    LOADK(av, bv, 0);                                                         \
    if (STG) { STA(An, 2, k0n); STA(An, 3, k0n); STB(Bn, 1, k0n); }           \
    LOADK(aw, bw, 1);                                                         \
    __builtin_amdgcn_s_setprio(1);                                            \
    MFMAK(av, bv);                                                            \
    MFMAK(aw, bw);                                                            \
    __builtin_amdgcn_s_setprio(0);                                            \
    asm volatile("s_waitcnt " VM ::: "memory");                               \
    __builtin_amdgcn_s_barrier();                                             \
  }

__device__ __forceinline__ void gemm_loop(const _Float16* __restrict__ A,
                                          const _Float16* __restrict__ W,
                                          int K, int kbase, int nt, int row0,
                                          int col0, int tid, _Float16* lds_,
                                          f32x4 (&acc)[4][4]) {
  const int lane = tid & 63;
  const int wave = tid >> 6;   // 0..7
  const int wr = wave >> 1;    // 0..3 : 64-row slice
  const int wc = wave & 1;     // 0..1 : 64-col slice
  const int fr = lane & 15;
  const int q2 = lane >> 4;
  const int srow = tid >> 3;                       // staging row 0..63
  const int sgc = ((tid & 7) ^ (srow & 7)) * 8;    // pre-swizzled chunk

  // prologue: stage tiles 0 and 1 (12 loads), validate tile 0.
  {
    _Float16* A0 = lds_;
    _Float16* B0 = lds_ + ABOFF;
    STA(A0, 0, kbase); STA(A0, 1, kbase); STA(A0, 2, kbase); STA(A0, 3, kbase);
    STB(B0, 0, kbase); STB(B0, 1, kbase);
    _Float16* A1 = lds_ + BUFSZ;
    _Float16* B1 = A1 + ABOFF;
    STA(A1, 0, kbase + 64); STA(A1, 1, kbase + 64);
    STA(A1, 2, kbase + 64); STA(A1, 3, kbase + 64);
    STB(B1, 0, kbase + 64); STB(B1, 1, kbase + 64);
    asm volatile("s_waitcnt vmcnt(6)" ::: "memory");  // tile 0 landed
    __builtin_amdgcn_s_barrier();
  }

  int cur = 0, nxt = 2;
  for (int t = 0; t + 2 < nt; ++t) {
    GITER1(1, "vmcnt(6)", kbase + (t + 2) * 64);
    cur = cur == 2 ? 0 : cur + 1;
    nxt = nxt == 2 ? 0 : nxt + 1;
  }
  GITER1(0, "vmcnt(0)", 0);  // t = nt-2: drain, validates tile nt-1
  cur = cur == 2 ? 0 : cur + 1;
  GITER1(0, "vmcnt(0)", 0);  // t = nt-1: vmcnt(0) is free (0 outstanding)
}

// ---------------------------------------------------------------------------
// Layers 0-2: C = relu(bn(A[256,K] @ W[128,K]^T)) -> fp16 into H.
// Grid dim3(32,8), 512 threads, 144 KB dynamic LDS (1 block/CU, 8 waves).
// launch_bounds minWavesPerEU=1: =2 caps unified regs at 128 -> spill (R7).
__launch_bounds__(512, 1) __global__
void gemm_bn_8ph(const _Float16* __restrict__ A, int K,
                 const _Float16* __restrict__ W,
                 const float* __restrict__ bias,
                 const float* __restrict__ g, const float* __restrict__ be,
                 const float* __restrict__ rm, const float* __restrict__ rv,
                 _Float16* __restrict__ outH, int outOff) {
  extern __shared__ _Float16 lds_[];
  const int tid = threadIdx.x;
  const int lane = tid & 63;
  const int wave = tid >> 6;
  const int wr = wave >> 1;
  const int wc = wave & 1;
  const int fr = lane & 15;
  const int q2 = lane >> 4;
  const int row0 = blockIdx.x * 256;
  const int col0 = blockIdx.y * 128;

  f32x4 acc[4][4] = {};
  gemm_loop(A, W, K, 0, K >> 6, row0, col0, tid, lds_, acc);

  // Epilogue. C/D layout: col = lane&15, row = (lane>>4)*4 + reg.
#pragma unroll
  for (int tn = 0; tn < 4; ++tn) {
    const int n = col0 + wc * 64 + tn * 16 + fr;
    const float alpha = g[n] * rsqrtf(rv[n] + 1e-5f);
    const float beta = (bias[n] - rm[n]) * alpha + be[n];
#pragma unroll
    for (int tm = 0; tm < 4; ++tm) {
      const int rbase = row0 + wr * 64 + tm * 16 + q2 * 4;
#pragma unroll
      for (int r = 0; r < 4; ++r) {
        float v = acc[tm][tn][r] * alpha + beta;
        v = fmaxf(v, 0.0f);
        outH[(size_t)(rbase + r) * LDH + outOff + n] = f2h(v);
      }
    }
  }
}

// ---------------------------------------------------------------------------
// Layer 3: same loop, splitK=4 (832 = 13*64 per slice). Grid dim3(32,8):
// cb=by&1 (col tile), ks=by>>1. Partials atomicAdd into out (bias
// pre-applied by prep).
__launch_bounds__(512, 1) __global__
void gemm_out_8ph(const _Float16* __restrict__ A,
                  const _Float16* __restrict__ W, float* __restrict__ out) {
  extern __shared__ _Float16 lds_[];
  const int tid = threadIdx.x;
  const int lane = tid & 63;
  const int wave = tid >> 6;
  const int wr = wave >> 1;
  const int wc = wave & 1;
  const int fr = lane & 15;
  const int q2 = lane >> 4;
  const int row0 = blockIdx.x * 256;
  const int cb = blockIdx.y & 1;
  const int ks = blockIdx.y >> 1;
  const int col0 = cb * 128;
  const int K = 3328;

  f32x4 acc[4][4] = {};
  gemm_loop(A, W, K, ks * 832, 13, row0, col0, tid, lds_, acc);

#pragma unroll
  for (int tn = 0; tn < 4; ++tn) {
    const int n = col0 + wc * 64 + tn * 16 + fr;
#pragma unroll
    for (int tm = 0; tm < 4; ++tm) {
      const int rbase = row0 + wr * 64 + tm * 16 + q2 * 4;
#pragma unroll
      for (int r = 0; r < 4; ++r)
        atomicAdd(&out[(size_t)(rbase + r) * 256 + n], acc[tm][tn][r]);
    }
  }
}

// ---------------------------------------------------------------------------
// ragged segment softmax, in place on out[8192][256]; 4 rows/block (1/wave).
__global__ void segsoftmax_kernel(float* __restrict__ out,
                                  const int* __restrict__ segids) {
  __shared__ float vals[4][256];
  __shared__ float red[4][10];
  const int w = threadIdx.x >> 6;
  const int l = threadIdx.x & 63;
  const int row = blockIdx.x * 4 + w;
  float4 v = *(float4*)&out[(size_t)row * 256 + l * 4];
  *(float4*)&vals[w][l * 4] = v;
  __syncthreads();
  if (l < 10) {
    float m = -1e30f;
    for (int j = c_bnd[l]; j < c_bnd[l + 1]; ++j) m = fmaxf(m, vals[w][j]);
    red[w][l] = m;
  }
  __syncthreads();
  const int4 s4 = *(const int4*)&segids[l * 4];
  float4 e;
  e.x = expf(v.x - red[w][s4.x]);
  e.y = expf(v.y - red[w][s4.y]);
  e.z = expf(v.z - red[w][s4.z]);
  e.w = expf(v.w - red[w][s4.w]);
  *(float4*)&vals[w][l * 4] = e;
  __syncthreads();
  if (l < 10) {
    float s = 0.0f;
    for (int j = c_bnd[l]; j < c_bnd[l + 1]; ++j) s += vals[w][j];
    red[w][l] = s;
  }
  __syncthreads();
  float4 o;
  o.x = e.x / red[w][s4.x];
  o.y = e.y / red[w][s4.y];
  o.z = e.z / red[w][s4.z];
  o.w = e.w / red[w][s4.w];
  *(float4*)&out[(size_t)row * 256 + l * 4] = o;
}

// ---------------------------------------------------------------------------
extern "C" void kernel_launch(void* const* d_in, const int* in_sizes, int n_in,
                              void* d_out, int out_size, void* d_ws,
                              size_t ws_size, hipStream_t stream) {
  const float* x = (const float*)d_in[0];
  const float* W0 = (const float*)d_in[1];
  const float* b0 = (const float*)d_in[2];
  const float* g0 = (const float*)d_in[3];
  const float* be0 = (const float*)d_in[4];
  const float* rm0 = (const float*)d_in[5];
  const float* rv0 = (const float*)d_in[6];
  const float* W1 = (const float*)d_in[7];
  const float* b1 = (const float*)d_in[8];
  const float* g1 = (const float*)d_in[9];
  const float* be1 = (const float*)d_in[10];
  const float* rm1 = (const float*)d_in[11];
  const float* rv1 = (const float*)d_in[12];
  const float* W2 = (const float*)d_in[13];
  const float* b2 = (const float*)d_in[14];
  const float* g2 = (const float*)d_in[15];
  const float* be2 = (const float*)d_in[16];
  const float* rm2 = (const float*)d_in[17];
  const float* rv2 = (const float*)d_in[18];
  const float* W3 = (const float*)d_in[19];
  const float* b3 = (const float*)d_in[20];
  const int* seg = (const int*)d_in[21];
  float* out = (float*)d_out;

  // ws (fp16): H[8192*3328] | Wh0 | Wh1 | Wh2 | Wh3  (~64.1 MB)
  _Float16* H = (_Float16*)d_ws;
  size_t off = (size_t)NROWS * LDH;
  _Float16* Wh0 = H + off; off += 1024 * 256;
  _Float16* Wh1 = H + off; off += 1024 * 1280;
  _Float16* Wh2 = H + off; off += 1024 * 2304;
  _Float16* Wh3 = H + off;

  static bool attr_done = false;
  if (!attr_done) {
    hipFuncSetAttribute(reinterpret_cast<const void*>(gemm_bn_8ph),
                        hipFuncAttributeMaxDynamicSharedMemorySize, 147456);
    hipFuncSetAttribute(reinterpret_cast<const void*>(gemm_out_8ph),
                        hipFuncAttributeMaxDynamicSharedMemorySize, 147456);
    attr_done = true;
  }

  // cumulative float4 counts: W0, W1, W2, W3, x, out-init
  const int n0 = 65536, n1 = n0 + 327680, n2 = n1 + 589824, n3 = n2 + 212992;
  const int n4 = n3 + 524288, n5 = n4 + 524288;
  prep_kernel<<<(n5 + 255) / 256, 256, 0, stream>>>(
      W0, W1, W2, W3, x, b3, Wh0, Wh1, Wh2, Wh3, H, out, n0, n1, n2, n3, n4,
      n5);

  gemm_bn_8ph<<<dim3(32, 8), 512, 147456, stream>>>(
      H + 3072, 256, Wh0, b0, g0, be0, rm0, rv0, H, 2048);
  gemm_bn_8ph<<<dim3(32, 8), 512, 147456, stream>>>(
      H + 2048, 1280, Wh1, b1, g1, be1, rm1, rv1, H, 1024);
  gemm_bn_8ph<<<dim3(32, 8), 512, 147456, stream>>>(
      H + 1024, 2304, Wh2, b2, g2, be2, rm2, rv2, H, 0);
  gemm_out_8ph<<<dim3(32, 8), 512, 147456, stream>>>(H, Wh3, out);
  segsoftmax_kernel<<<2048, 256, 0, stream>>>(out, seg);
}